// Round 1
// baseline (300.011 us; speedup 1.0000x reference)
//
#include <hip/hip_runtime.h>

#define BATCH 1024
#define N_IN 1024
#define TOTAL 18432   // 1024 + 8*2048 + 1024
#define BLOCK 512

__global__ __launch_bounds__(BLOCK) void net_kernel(
    const float* __restrict__ X,
    const float* __restrict__ wptr,
    const int* __restrict__ cidx,
    float* __restrict__ out)
{
    __shared__ float vals[TOTAL];   // 72 KB: full value history for one batch row
    const int row = blockIdx.x;
    const float w = wptr[0];

    // Stage this row of X into LDS (coalesced float4)
    {
        const float4* src = reinterpret_cast<const float4*>(X + (size_t)row * N_IN);
        float4* dst = reinterpret_cast<float4*>(vals);
        for (int i = threadIdx.x; i < N_IN / 4; i += BLOCK) dst[i] = src[i];
    }
    __syncthreads();

    int off = N_IN;   // number of valid columns so far
    int ptr = 0;      // row offset into child_idx
    #pragma unroll
    for (int li = 0; li < 9; ++li) {
        const int sz = (li == 8) ? 1024 : 2048;
        // Each thread computes neurons n, n+BLOCK, ... of this layer.
        // Writes land in [off, off+sz); all gather indices are < off -> no race.
        for (int n = threadIdx.x; n < sz; n += BLOCK) {
            const int4* ip = reinterpret_cast<const int4*>(cidx + (size_t)(ptr + n) * 32);
            float s0 = 0.f, s1 = 0.f, s2 = 0.f, s3 = 0.f;
            #pragma unroll
            for (int j = 0; j < 8; ++j) {
                const int4 v = ip[j];
                s0 += vals[v.x];
                s1 += vals[v.y];
                s2 += vals[v.z];
                s3 += vals[v.w];
            }
            vals[off + n] = tanhf(w * ((s0 + s1) + (s2 + s3)));
        }
        __syncthreads();
        off += sz;
        ptr += sz;
    }

    // Output = last 1024 columns
    {
        const float4* src = reinterpret_cast<const float4*>(vals + TOTAL - 1024);
        float4* dst = reinterpret_cast<float4*>(out + (size_t)row * 1024);
        for (int i = threadIdx.x; i < 1024 / 4; i += BLOCK) dst[i] = src[i];
    }
}

extern "C" void kernel_launch(void* const* d_in, const int* in_sizes, int n_in,
                              void* d_out, int out_size, void* d_ws, size_t ws_size,
                              hipStream_t stream)
{
    const float* X    = (const float*)d_in[0];
    const float* w    = (const float*)d_in[1];
    const int*   cidx = (const int*)d_in[2];
    float* out = (float*)d_out;

    hipLaunchKernelGGL(net_kernel, dim3(BATCH), dim3(BLOCK), 0, stream,
                       X, w, cidx, out);
}

// Round 2
// 192.778 us; speedup vs baseline: 1.5563x; 1.5563x over previous
//
#include <hip/hip_runtime.h>

#define BATCH 1024
#define N_IN 1024
#define TOTAL 18432   // 1024 + 8*2048 + 1024
#define BLOCK 1024

// 2 batch rows per block, interleaved in LDS as float2 -> every gather is a
// ds_read_b64 serving both rows (half the LDS instruction count per row).
__global__ __launch_bounds__(BLOCK) void net_kernel(
    const float* __restrict__ X,
    const float* __restrict__ wptr,
    const int* __restrict__ cidx,
    float* __restrict__ out)
{
    __shared__ float2 vals[TOTAL];   // 144 KB
    const int rowA = blockIdx.x * 2;
    const float w = wptr[0];

    // Stage rows A,B of X interleaved (coalesced float4 global reads)
    {
        const float4* xa = reinterpret_cast<const float4*>(X + (size_t)rowA * N_IN);
        const float4* xb = reinterpret_cast<const float4*>(X + (size_t)(rowA + 1) * N_IN);
        for (int t = threadIdx.x; t < N_IN / 4; t += BLOCK) {
            float4 a = xa[t], b = xb[t];
            vals[4 * t + 0] = make_float2(a.x, b.x);
            vals[4 * t + 1] = make_float2(a.y, b.y);
            vals[4 * t + 2] = make_float2(a.z, b.z);
            vals[4 * t + 3] = make_float2(a.w, b.w);
        }
    }
    __syncthreads();

    int off = N_IN;   // valid columns so far
    int ptr = 0;      // row offset into child_idx
    #pragma unroll
    for (int li = 0; li < 9; ++li) {
        const int sz = (li == 8) ? 1024 : 2048;
        // Writes land in [off, off+sz); all gather indices are < off -> no race.
        for (int n = threadIdx.x; n < sz; n += BLOCK) {
            const int4* ip = reinterpret_cast<const int4*>(cidx + (size_t)(ptr + n) * 32);
            float sA0 = 0.f, sA1 = 0.f, sB0 = 0.f, sB1 = 0.f;
            #pragma unroll
            for (int j = 0; j < 8; ++j) {
                const int4 v = ip[j];
                float2 a = vals[v.x];
                float2 b = vals[v.y];
                float2 c = vals[v.z];
                float2 d = vals[v.w];
                sA0 += a.x + b.x;  sA1 += c.x + d.x;
                sB0 += a.y + b.y;  sB1 += c.y + d.y;
            }
            vals[off + n] = make_float2(tanhf(w * (sA0 + sA1)),
                                        tanhf(w * (sB0 + sB1)));
        }
        __syncthreads();
        off += sz;
        ptr += sz;
    }

    // Output = last 1024 columns of each row (de-interleave)
    {
        float* oA = out + (size_t)rowA * 1024;
        float* oB = out + (size_t)(rowA + 1) * 1024;
        const float2* src = vals + (TOTAL - 1024);
        for (int t = threadIdx.x; t < 1024; t += BLOCK) {
            float2 v = src[t];
            oA[t] = v.x;
            oB[t] = v.y;
        }
    }
}

extern "C" void kernel_launch(void* const* d_in, const int* in_sizes, int n_in,
                              void* d_out, int out_size, void* d_ws, size_t ws_size,
                              hipStream_t stream)
{
    const float* X    = (const float*)d_in[0];
    const float* w    = (const float*)d_in[1];
    const int*   cidx = (const int*)d_in[2];
    float* out = (float*)d_out;

    hipLaunchKernelGGL(net_kernel, dim3(BATCH / 2), dim3(BLOCK), 0, stream,
                       X, w, cidx, out);
}

// Round 4
// 166.658 us; speedup vs baseline: 1.8002x; 1.1567x over previous
//
#include <hip/hip_runtime.h>

#define BATCH 1024
#define N_IN 1024
#define TOTAL 18432   // 1024 + 8*2048 + 1024
#define BLOCK 1024
#define NNEUR 17408   // 8*2048 + 1024

__device__ __forceinline__ float fast_tanh(float x) {
    // tanh(x) = 1 - 2/(1+exp(2x)) ; exact at saturation, ~1e-7 rel error
    float e = __expf(2.0f * x);
    return 1.0f - 2.0f / (1.0f + e);
}

// ---------- Preprocessing: bank-stagger sort + transpose into d_ws ----------
// For each neuron: counting-sort its 32 indices by LDS wide-bank (idx & 15,
// since vals is float2 -> 8 B/elem -> bank = idx % 16), rotate by (lane/2)
// so concurrent lanes hit staggered bank quantiles, then write transposed
// [group g][neuron n] as int4 for perfectly coalesced index loads.
__global__ void prep_kernel(const int* __restrict__ cidx, int4* __restrict__ idxT) {
    int m = blockIdx.x * blockDim.x + threadIdx.x;
    if (m >= NNEUR) return;
    int layer = min(m >> 11, 8);
    int nloc  = m - (layer << 11);
    int sz    = (layer == 8) ? 1024 : 2048;
    int ptr   = layer << 11;          // row offset of this layer in cidx

    const int* src = cidx + (size_t)m * 32;
    int v[32];
    #pragma unroll
    for (int j = 0; j < 32; ++j) v[j] = src[j];

    int cnt[16];
    #pragma unroll
    for (int b = 0; b < 16; ++b) cnt[b] = 0;
    #pragma unroll
    for (int j = 0; j < 32; ++j) cnt[v[j] & 15]++;
    int st[16]; int acc = 0;
    #pragma unroll
    for (int b = 0; b < 16; ++b) { st[b] = acc; acc += cnt[b]; }
    int sorted[32];
    #pragma unroll
    for (int j = 0; j < 32; ++j) sorted[st[v[j] & 15]++] = v[j];

    int r = (nloc & 63) >> 1;         // lane-dependent rotation, 0..31
    int4* dst = idxT + (size_t)ptr * 8;   // 8 int4 per neuron
    #pragma unroll
    for (int g = 0; g < 8; ++g) {
        int4 o;
        o.x = sorted[(4 * g + 0 + r) & 31];
        o.y = sorted[(4 * g + 1 + r) & 31];
        o.z = sorted[(4 * g + 2 + r) & 31];
        o.w = sorted[(4 * g + 3 + r) & 31];
        dst[(size_t)g * sz + nloc] = o;   // coalesced: consecutive n -> consecutive int4
    }
}

// ---------- Main kernel, transposed-index path ----------
__global__ __launch_bounds__(BLOCK) void net_kernel_t(
    const float* __restrict__ X,
    const float* __restrict__ wptr,
    const int4* __restrict__ idxT,
    float* __restrict__ out)
{
    __shared__ float2 vals[TOTAL];   // 144 KB, rows (A,B) interleaved
    const int rowA = blockIdx.x * 2;
    const float w = wptr[0];
    const int t = threadIdx.x;

    {
        const float4* xa = reinterpret_cast<const float4*>(X + (size_t)rowA * N_IN);
        const float4* xb = reinterpret_cast<const float4*>(X + (size_t)(rowA + 1) * N_IN);
        for (int i = t; i < N_IN / 4; i += BLOCK) {
            float4 a = xa[i], b = xb[i];
            vals[4 * i + 0] = make_float2(a.x, b.x);
            vals[4 * i + 1] = make_float2(a.y, b.y);
            vals[4 * i + 2] = make_float2(a.z, b.z);
            vals[4 * i + 3] = make_float2(a.w, b.w);
        }
    }
    __syncthreads();

    int off = N_IN;
    const int4* L = idxT;
    #pragma unroll
    for (int li = 0; li < 9; ++li) {
        const int sz = (li == 8) ? 1024 : 2048;
        if (sz == 2048) {
            // two neurons per thread, interleaved for ILP
            const int n0 = t, n1 = t + 1024;
            float a0x = 0.f, a0y = 0.f, a1x = 0.f, a1y = 0.f;
            #pragma unroll
            for (int g = 0; g < 8; ++g) {
                int4 i0 = L[(size_t)g * 2048 + n0];
                int4 i1 = L[(size_t)g * 2048 + n1];
                float2 p = vals[i0.x], q = vals[i0.y], u = vals[i0.z], s = vals[i0.w];
                a0x += (p.x + q.x) + (u.x + s.x);
                a0y += (p.y + q.y) + (u.y + s.y);
                p = vals[i1.x]; q = vals[i1.y]; u = vals[i1.z]; s = vals[i1.w];
                a1x += (p.x + q.x) + (u.x + s.x);
                a1y += (p.y + q.y) + (u.y + s.y);
            }
            vals[off + n0] = make_float2(fast_tanh(w * a0x), fast_tanh(w * a0y));
            vals[off + n1] = make_float2(fast_tanh(w * a1x), fast_tanh(w * a1y));
        } else {
            const int n0 = t;
            float a0x = 0.f, a0y = 0.f;
            #pragma unroll
            for (int g = 0; g < 8; ++g) {
                int4 i0 = L[(size_t)g * 1024 + n0];
                float2 p = vals[i0.x], q = vals[i0.y], u = vals[i0.z], s = vals[i0.w];
                a0x += (p.x + q.x) + (u.x + s.x);
                a0y += (p.y + q.y) + (u.y + s.y);
            }
            vals[off + n0] = make_float2(fast_tanh(w * a0x), fast_tanh(w * a0y));
        }
        __syncthreads();
        off += sz;
        L += (size_t)sz * 8;
    }

    {
        float* oA = out + (size_t)rowA * 1024;
        float* oB = out + (size_t)(rowA + 1) * 1024;
        const float2* src = vals + (TOTAL - 1024);
        for (int i = t; i < 1024; i += BLOCK) {
            float2 v = src[i];
            oA[i] = v.x;
            oB[i] = v.y;
        }
    }
}

// ---------- Fallback (ws too small): round-2 structure + fast_tanh ----------
__global__ __launch_bounds__(BLOCK) void net_kernel_f(
    const float* __restrict__ X,
    const float* __restrict__ wptr,
    const int* __restrict__ cidx,
    float* __restrict__ out)
{
    __shared__ float2 vals[TOTAL];
    const int rowA = blockIdx.x * 2;
    const float w = wptr[0];
    const int t = threadIdx.x;
    {
        const float4* xa = reinterpret_cast<const float4*>(X + (size_t)rowA * N_IN);
        const float4* xb = reinterpret_cast<const float4*>(X + (size_t)(rowA + 1) * N_IN);
        for (int i = t; i < N_IN / 4; i += BLOCK) {
            float4 a = xa[i], b = xb[i];
            vals[4 * i + 0] = make_float2(a.x, b.x);
            vals[4 * i + 1] = make_float2(a.y, b.y);
            vals[4 * i + 2] = make_float2(a.z, b.z);
            vals[4 * i + 3] = make_float2(a.w, b.w);
        }
    }
    __syncthreads();
    int off = N_IN, ptr = 0;
    #pragma unroll
    for (int li = 0; li < 9; ++li) {
        const int sz = (li == 8) ? 1024 : 2048;
        for (int n = t; n < sz; n += BLOCK) {
            const int4* ip = reinterpret_cast<const int4*>(cidx + (size_t)(ptr + n) * 32);
            float sx = 0.f, sy = 0.f;
            #pragma unroll
            for (int j = 0; j < 8; ++j) {
                const int4 v = ip[j];
                float2 a = vals[v.x], b = vals[v.y], c = vals[v.z], d = vals[v.w];
                sx += (a.x + b.x) + (c.x + d.x);
                sy += (a.y + b.y) + (c.y + d.y);
            }
            vals[off + n] = make_float2(fast_tanh(w * sx), fast_tanh(w * sy));
        }
        __syncthreads();
        off += sz;
        ptr += sz;
    }
    {
        float* oA = out + (size_t)rowA * 1024;
        float* oB = out + (size_t)(rowA + 1) * 1024;
        const float2* src = vals + (TOTAL - 1024);
        for (int i = t; i < 1024; i += BLOCK) {
            float2 v = src[i];
            oA[i] = v.x;
            oB[i] = v.y;
        }
    }
}

extern "C" void kernel_launch(void* const* d_in, const int* in_sizes, int n_in,
                              void* d_out, int out_size, void* d_ws, size_t ws_size,
                              hipStream_t stream)
{
    const float* X    = (const float*)d_in[0];
    const float* w    = (const float*)d_in[1];
    const int*   cidx = (const int*)d_in[2];
    float* out = (float*)d_out;

    const size_t need = (size_t)NNEUR * 32 * sizeof(int);   // 2.23 MB
    if (ws_size >= need) {
        int4* idxT = (int4*)d_ws;
        hipLaunchKernelGGL(prep_kernel, dim3((NNEUR + 255) / 256), dim3(256), 0, stream,
                           cidx, idxT);
        hipLaunchKernelGGL(net_kernel_t, dim3(BATCH / 2), dim3(BLOCK), 0, stream,
                           X, w, idxT, out);
    } else {
        hipLaunchKernelGGL(net_kernel_f, dim3(BATCH / 2), dim3(BLOCK), 0, stream,
                           X, w, cidx, out);
    }
}

// Round 5
// 130.902 us; speedup vs baseline: 2.2919x; 1.2732x over previous
//
#include <hip/hip_runtime.h>

#define BATCH 1024
#define N_IN 1024
#define TOTAL 18432   // 1024 + 8*2048 + 1024
#define BLOCK 1024
#define NNEUR 17408   // 8*2048 + 1024

__device__ __forceinline__ float fast_tanh(float x) {
    // tanh(x) = 1 - 2/(1+exp(2x)) ; exact at saturation, ~1e-7 rel error
    float e = __expf(2.0f * x);
    return 1.0f - 2.0f / (1.0f + e);
}

// ---------- Preprocessing: pure transpose into d_ws (no sort) ----------
// Writes index groups as [layer][g][neuron] int4 so the main kernel's index
// loads are perfectly coalesced (consecutive lanes -> consecutive int4).
__global__ void prep_kernel(const int4* __restrict__ cidx4, int4* __restrict__ idxT) {
    int m = blockIdx.x * blockDim.x + threadIdx.x;
    if (m >= NNEUR) return;
    int layer = min(m >> 11, 8);
    int nloc  = m - (layer << 11);
    int sz    = (layer == 8) ? 1024 : 2048;
    int ptr   = layer << 11;              // neuron offset of this layer

    const int4* src = cidx4 + (size_t)m * 8;     // 8 int4 per neuron
    int4* dst = idxT + (size_t)ptr * 8;
    #pragma unroll
    for (int g = 0; g < 8; ++g) {
        dst[(size_t)g * sz + nloc] = src[g];     // coalesced writes
    }
}

// ---------- Main kernel, transposed-index path ----------
__global__ __launch_bounds__(BLOCK) void net_kernel_t(
    const float* __restrict__ X,
    const float* __restrict__ wptr,
    const int4* __restrict__ idxT,
    float* __restrict__ out)
{
    __shared__ float2 vals[TOTAL];   // 144 KB, rows (A,B) interleaved
    const int rowA = blockIdx.x * 2;
    const float w = wptr[0];
    const int t = threadIdx.x;

    {
        const float4* xa = reinterpret_cast<const float4*>(X + (size_t)rowA * N_IN);
        const float4* xb = reinterpret_cast<const float4*>(X + (size_t)(rowA + 1) * N_IN);
        for (int i = t; i < N_IN / 4; i += BLOCK) {
            float4 a = xa[i], b = xb[i];
            vals[4 * i + 0] = make_float2(a.x, b.x);
            vals[4 * i + 1] = make_float2(a.y, b.y);
            vals[4 * i + 2] = make_float2(a.z, b.z);
            vals[4 * i + 3] = make_float2(a.w, b.w);
        }
    }
    __syncthreads();

    int off = N_IN;
    const int4* L = idxT;
    #pragma unroll
    for (int li = 0; li < 9; ++li) {
        const int sz = (li == 8) ? 1024 : 2048;
        if (sz == 2048) {
            // two neurons per thread, interleaved for ILP
            const int n0 = t, n1 = t + 1024;
            float a0x = 0.f, a0y = 0.f, a1x = 0.f, a1y = 0.f;
            #pragma unroll
            for (int g = 0; g < 8; ++g) {
                int4 i0 = L[(size_t)g * 2048 + n0];
                int4 i1 = L[(size_t)g * 2048 + n1];
                float2 p = vals[i0.x], q = vals[i0.y], u = vals[i0.z], s = vals[i0.w];
                a0x += (p.x + q.x) + (u.x + s.x);
                a0y += (p.y + q.y) + (u.y + s.y);
                p = vals[i1.x]; q = vals[i1.y]; u = vals[i1.z]; s = vals[i1.w];
                a1x += (p.x + q.x) + (u.x + s.x);
                a1y += (p.y + q.y) + (u.y + s.y);
            }
            vals[off + n0] = make_float2(fast_tanh(w * a0x), fast_tanh(w * a0y));
            vals[off + n1] = make_float2(fast_tanh(w * a1x), fast_tanh(w * a1y));
        } else {
            const int n0 = t;
            float a0x = 0.f, a0y = 0.f;
            #pragma unroll
            for (int g = 0; g < 8; ++g) {
                int4 i0 = L[(size_t)g * 1024 + n0];
                float2 p = vals[i0.x], q = vals[i0.y], u = vals[i0.z], s = vals[i0.w];
                a0x += (p.x + q.x) + (u.x + s.x);
                a0y += (p.y + q.y) + (u.y + s.y);
            }
            vals[off + n0] = make_float2(fast_tanh(w * a0x), fast_tanh(w * a0y));
        }
        __syncthreads();
        off += sz;
        L += (size_t)sz * 8;
    }

    {
        float* oA = out + (size_t)rowA * 1024;
        float* oB = out + (size_t)(rowA + 1) * 1024;
        const float2* src = vals + (TOTAL - 1024);
        for (int i = t; i < 1024; i += BLOCK) {
            float2 v = src[i];
            oA[i] = v.x;
            oB[i] = v.y;
        }
    }
}

// ---------- Fallback (ws too small): round-2 structure + fast_tanh ----------
__global__ __launch_bounds__(BLOCK) void net_kernel_f(
    const float* __restrict__ X,
    const float* __restrict__ wptr,
    const int* __restrict__ cidx,
    float* __restrict__ out)
{
    __shared__ float2 vals[TOTAL];
    const int rowA = blockIdx.x * 2;
    const float w = wptr[0];
    const int t = threadIdx.x;
    {
        const float4* xa = reinterpret_cast<const float4*>(X + (size_t)rowA * N_IN);
        const float4* xb = reinterpret_cast<const float4*>(X + (size_t)(rowA + 1) * N_IN);
        for (int i = t; i < N_IN / 4; i += BLOCK) {
            float4 a = xa[i], b = xb[i];
            vals[4 * i + 0] = make_float2(a.x, b.x);
            vals[4 * i + 1] = make_float2(a.y, b.y);
            vals[4 * i + 2] = make_float2(a.z, b.z);
            vals[4 * i + 3] = make_float2(a.w, b.w);
        }
    }
    __syncthreads();
    int off = N_IN, ptr = 0;
    #pragma unroll
    for (int li = 0; li < 9; ++li) {
        const int sz = (li == 8) ? 1024 : 2048;
        for (int n = t; n < sz; n += BLOCK) {
            const int4* ip = reinterpret_cast<const int4*>(cidx + (size_t)(ptr + n) * 32);
            float sx = 0.f, sy = 0.f;
            #pragma unroll
            for (int j = 0; j < 8; ++j) {
                const int4 v = ip[j];
                float2 a = vals[v.x], b = vals[v.y], c = vals[v.z], d = vals[v.w];
                sx += (a.x + b.x) + (c.x + d.x);
                sy += (a.y + b.y) + (c.y + d.y);
            }
            vals[off + n] = make_float2(fast_tanh(w * sx), fast_tanh(w * sy));
        }
        __syncthreads();
        off += sz;
        ptr += sz;
    }
    {
        float* oA = out + (size_t)rowA * 1024;
        float* oB = out + (size_t)(rowA + 1) * 1024;
        const float2* src = vals + (TOTAL - 1024);
        for (int i = t; i < 1024; i += BLOCK) {
            float2 v = src[i];
            oA[i] = v.x;
            oB[i] = v.y;
        }
    }
}

extern "C" void kernel_launch(void* const* d_in, const int* in_sizes, int n_in,
                              void* d_out, int out_size, void* d_ws, size_t ws_size,
                              hipStream_t stream)
{
    const float* X    = (const float*)d_in[0];
    const float* w    = (const float*)d_in[1];
    const int*   cidx = (const int*)d_in[2];
    float* out = (float*)d_out;

    const size_t need = (size_t)NNEUR * 32 * sizeof(int);   // 2.23 MB
    if (ws_size >= need) {
        int4* idxT = (int4*)d_ws;
        hipLaunchKernelGGL(prep_kernel, dim3((NNEUR + 255) / 256), dim3(256), 0, stream,
                           (const int4*)cidx, idxT);
        hipLaunchKernelGGL(net_kernel_t, dim3(BATCH / 2), dim3(BLOCK), 0, stream,
                           X, w, idxT, out);
    } else {
        hipLaunchKernelGGL(net_kernel_f, dim3(BATCH / 2), dim3(BLOCK), 0, stream,
                           X, w, cidx, out);
    }
}